// Round 4
// baseline (343.854 us; speedup 1.0000x reference)
//
#include <hip/hip_runtime.h>

#define B_ 4
#define C_ 256
#define N_ 4096
#define D_ 64

typedef __bf16 bf16x8 __attribute__((ext_vector_type(8)));
typedef float floatx4 __attribute__((ext_vector_type(4)));
typedef unsigned short ushort8v __attribute__((ext_vector_type(8)));
typedef unsigned short ushort4v __attribute__((ext_vector_type(4)));
typedef unsigned short ushort2v __attribute__((ext_vector_type(2)));

static __device__ __forceinline__ unsigned short f2bf(float f) {
    unsigned int u = __builtin_bit_cast(unsigned int, f);
    u += 0x7fffu + ((u >> 16) & 1u);   // RNE
    return (unsigned short)(u >> 16);
}
static __device__ __forceinline__ float bf2f(unsigned short h) {
    unsigned int u = ((unsigned int)h) << 16;
    return __builtin_bit_cast(float, u);
}

// ---------------------------------------------------------------------------
// Projection GEMM: fp32 compute; f in [0,64) -> Q[b][n][d] bf16,
// [64,128) -> K[b][n][d] bf16, [128,384) -> V[b][c][n] bf16 (c-major).
// Grid (n-tile, f, b): the 3 f-blocks sharing one x slice get consecutive
// ids spaced by 32 (≡0 mod 8) -> same XCD -> x L2 reuse.
// V store now bounces through LDS so global writes are coalesced 256B rows
// (the R2/R3 scattered 16B V-store cost ~100 us).
// ---------------------------------------------------------------------------
__global__ __launch_bounds__(256) void proj_kernel(
    const float* __restrict__ x,
    const float* __restrict__ Wq, const float* __restrict__ bq,
    const float* __restrict__ Wk, const float* __restrict__ bk,
    const float* __restrict__ Wv, const float* __restrict__ bv,
    unsigned short* __restrict__ Qg, unsigned short* __restrict__ Kg,
    unsigned short* __restrict__ Vg)
{
    __shared__ __align__(16) char psm[17408];
    float (*As)[128] = (float (*)[128])psm;            // 8 KB
    float (*Bs)[128] = (float (*)[128])(psm + 8192);   // 8 KB
    unsigned short* Tv = (unsigned short*)psm;         // 64 x 132 bf16 (V bounce)

    const int n0 = blockIdx.x * 128;
    const int f0 = blockIdx.y * 128;
    const int b  = blockIdx.z;
    const int t  = threadIdx.x;
    const int iy = t >> 4;
    const int tx = t & 15;

    const float* xb = x + (size_t)b * C_ * N_;

    float bias[8];
#pragma unroll
    for (int s = 0; s < 4; ++s)
#pragma unroll
        for (int r = 0; r < 2; ++r) {
            int fg = f0 + 2*tx + 32*s + r;
            float bb;
            if (fg < 64)       bb = bq[fg];
            else if (fg < 128) bb = bk[fg - 64];
            else               bb = bv[fg - 128];
            bias[2*s + r] = bb;
        }

    float acc[8][8];
#pragma unroll
    for (int a = 0; a < 8; ++a)
#pragma unroll
        for (int q = 0; q < 8; ++q) acc[a][q] = 0.f;

    for (int c0 = 0; c0 < C_; c0 += 16) {
        __syncthreads();
#pragma unroll
        for (int k = 0; k < 2; ++k) {
            int e4  = t + 256*k;
            int cc  = e4 >> 5;
            int nn4 = (e4 & 31) << 2;
            float4 v4 = *(const float4*)(xb + (size_t)(c0 + cc)*N_ + n0 + nn4);
            *(float4*)&As[cc][nn4] = v4;
        }
#pragma unroll
        for (int k = 0; k < 2; ++k) {
            int e4  = t + 256*k;
            int fl  = e4 >> 2;
            int cc4 = (e4 & 3) << 2;
            int fg  = f0 + fl;
            const float* wrow = (fg < 64)  ? (Wq + (size_t)fg * C_)
                              : (fg < 128) ? (Wk + (size_t)(fg - 64) * C_)
                                           : (Wv + (size_t)(fg - 128) * C_);
            float4 w4 = *(const float4*)(wrow + c0 + cc4);
            Bs[cc4+0][fl] = w4.x;
            Bs[cc4+1][fl] = w4.y;
            Bs[cc4+2][fl] = w4.z;
            Bs[cc4+3][fl] = w4.w;
        }
        __syncthreads();
#pragma unroll
        for (int cc = 0; cc < 16; ++cc) {
            float4 a0 = *(const float4*)&As[cc][iy*8];
            float4 a1 = *(const float4*)&As[cc][iy*8 + 4];
            float av[8] = {a0.x,a0.y,a0.z,a0.w,a1.x,a1.y,a1.z,a1.w};
            float bvv[8];
#pragma unroll
            for (int s = 0; s < 4; ++s) {
                float2 b2 = *(const float2*)&Bs[cc][2*tx + 32*s];
                bvv[2*s] = b2.x; bvv[2*s+1] = b2.y;
            }
#pragma unroll
            for (int a = 0; a < 8; ++a)
#pragma unroll
                for (int q = 0; q < 8; ++q)
                    acc[a][q] += av[a] * bvv[q];
        }
    }

    if (f0 < 128) {
        // Q/K: [n][64] bf16, ushort2 per (s) -> 64B per 16-lane group
#pragma unroll
        for (int a = 0; a < 8; ++a) {
            int n = n0 + iy*8 + a;
#pragma unroll
            for (int s = 0; s < 4; ++s) {
                int fg = 2*tx + 32*s;
                ushort2v u2;
                u2.x = f2bf(acc[a][2*s]   + bias[2*s]);
                u2.y = f2bf(acc[a][2*s+1] + bias[2*s+1]);
                unsigned short* dst = (fg < 64)
                    ? (Qg + ((size_t)b*N_ + n)*D_ + fg)
                    : (Kg + ((size_t)b*N_ + n)*D_ + (fg - 64));
                *(ushort2v*)dst = u2;
            }
        }
    } else {
        // V: LDS bounce in two 64-channel halves, then coalesced 256B rows
        const int cbase = f0 - 128;
#pragma unroll
        for (int H = 0; H < 2; ++H) {
            __syncthreads();   // prior As/Bs (or Tv) reads done
#pragma unroll
            for (int sh = 0; sh < 2; ++sh) {
                int s = 2*H + sh;
#pragma unroll
                for (int r = 0; r < 2; ++r) {
                    int ch = 2*tx + 32*sh + r;          // channel within half
                    ushort4v u;
#pragma unroll
                    for (int a = 0; a < 4; ++a)
                        u[a] = f2bf(acc[a][2*s + r] + bias[2*s + r]);
                    *(ushort4v*)&Tv[ch*132 + iy*8] = u;
#pragma unroll
                    for (int a = 0; a < 4; ++a)
                        u[a] = f2bf(acc[4 + a][2*s + r] + bias[2*s + r]);
                    *(ushort4v*)&Tv[ch*132 + iy*8 + 4] = u;
                }
            }
            __syncthreads();
#pragma unroll
            for (int kk = 0; kk < 4; ++kk) {
                int e  = t + 256*kk;        // 0..1023
                int cr = e >> 4;            // 0..63
                int n8 = (e & 15) * 8;      // 0..120
                ushort4v x0 = *(const ushort4v*)&Tv[cr*132 + n8];
                ushort4v x1 = *(const ushort4v*)&Tv[cr*132 + n8 + 4];
                ushort8v o8;
#pragma unroll
                for (int q = 0; q < 4; ++q) { o8[q] = x0[q]; o8[4+q] = x1[q]; }
                *(ushort8v*)(Vg + ((size_t)b*C_ + cbase + 64*H + cr)*N_
                             + n0 + n8) = o8;
            }
        }
    }
}

// ---------------------------------------------------------------------------
// MFMA flash attention, split-K (S = gridDim.y). Block = (64-query tile,
// key-slice, batch); 4 waves. S-phase computes S^T = K*Q (operand-swapped
// MFMA, identical loads) so queries sit on lane&15: softmax reduction is
// in-register + 2 shfl_xor, and P lands in LDS A-frag layout via direct b64
// stores (no pack shuffles). One barrier per chunk, double-buffered P.
// ---------------------------------------------------------------------------
__global__ __launch_bounds__(256, 3) void flash_kernel(
    const unsigned short* __restrict__ Qg, const unsigned short* __restrict__ Kg,
    const unsigned short* __restrict__ Vg,
    unsigned short* __restrict__ Opart, float* __restrict__ ML)
{
    __shared__ __align__(16) unsigned short PA[2][8 * 64 * 8];
    __shared__ float AL[2][64];
    __shared__ float LL[64];

    const int tile = blockIdx.x;
    const int half = blockIdx.y;
    const int S    = gridDim.y;
    const int b    = blockIdx.z;
    const int n0   = tile * 64;
    const int t    = threadIdx.x;
    const int w    = t >> 6;
    const int lane = t & 63;
    const int g    = lane >> 4;
    const int m    = lane & 15;

    const unsigned short* Qb = Qg + ((size_t)b*N_ + n0)*D_;
    const unsigned short* Kb = Kg + (size_t)b*N_*D_;
    const unsigned short* Vb = Vg + (size_t)b*C_*N_;

    const int cstart = (64 * half) / S;
    const int cend   = (64 * (half + 1)) / S;

    bf16x8 qf[2];
#pragma unroll
    for (int ks = 0; ks < 2; ++ks)
        qf[ks] = *(const bf16x8*)(Qb + (size_t)(16*w + m)*D_ + 32*ks + 8*g);

    floatx4 accO[4][4];
#pragma unroll
    for (int rt = 0; rt < 4; ++rt)
#pragma unroll
        for (int ct = 0; ct < 4; ++ct)
            accO[rt][ct] = (floatx4){0.f, 0.f, 0.f, 0.f};

    float mrow = -1e30f, lrow = 0.f;

    bf16x8 kf[2][4];
#pragma unroll
    for (int ks = 0; ks < 2; ++ks)
#pragma unroll
        for (int jt = 0; jt < 4; ++jt)
            kf[ks][jt] = *(const bf16x8*)(Kb + (size_t)(cstart*64 + 16*jt + m)*D_
                                          + 32*ks + 8*g);

    for (int t64 = cstart; t64 < cend; ++t64) {
        const int j0  = t64 * 64;
        const int buf = (t64 - cstart) & 1;

        bf16x8 vf[2][4];
#pragma unroll
        for (int ks = 0; ks < 2; ++ks)
#pragma unroll
            for (int ct = 0; ct < 4; ++ct)
                vf[ks][ct] = *(const bf16x8*)(Vb + (size_t)(64*w + 16*ct + m)*N_
                                              + j0 + 32*ks + 8*g);

        // S^T = K*Q: col=lane&15=query, row=4g+r = key(16jt+4g+r)
        floatx4 accST[4];
#pragma unroll
        for (int jt = 0; jt < 4; ++jt) accST[jt] = (floatx4){0.f, 0.f, 0.f, 0.f};
#pragma unroll
        for (int ks = 0; ks < 2; ++ks)
#pragma unroll
            for (int jt = 0; jt < 4; ++jt)
                accST[jt] = __builtin_amdgcn_mfma_f32_16x16x32_bf16(
                                kf[ks][jt], qf[ks], accST[jt], 0, 0, 0);

        {
            int j1 = (j0 + 64) & (N_ - 1);
#pragma unroll
            for (int ks = 0; ks < 2; ++ks)
#pragma unroll
                for (int jt = 0; jt < 4; ++jt)
                    kf[ks][jt] = *(const bf16x8*)(Kb + (size_t)(j1 + 16*jt + m)*D_
                                                  + 32*ks + 8*g);
        }

        // ---- online softmax: in-register over 16 keys/lane + 2 shfls ----
        float mx = -1e30f;
#pragma unroll
        for (int jt = 0; jt < 4; ++jt)
#pragma unroll
            for (int r = 0; r < 4; ++r) mx = fmaxf(mx, accST[jt][r]);
        mx = fmaxf(mx, __shfl_xor(mx, 16));
        mx = fmaxf(mx, __shfl_xor(mx, 32));
        float mnew  = fmaxf(mrow, mx);
        float alpha = __expf(mrow - mnew);
        mrow = mnew;
        float p[4][4];
        float rs = 0.f;
#pragma unroll
        for (int jt = 0; jt < 4; ++jt)
#pragma unroll
            for (int r = 0; r < 4; ++r) {
                float e = __expf(accST[jt][r] - mnew);
                p[jt][r] = e;
                rs += e;
            }
        rs += __shfl_xor(rs, 16);
        rs += __shfl_xor(rs, 32);
        lrow = lrow * alpha + rs;

        if (g == 0) AL[buf][16*w + m] = alpha;

        // P -> LDS, direct b64 stores into A-frag layout (no shuffles).
        // writer key 16jt+4g+r == reader key 32ks+8gt+j (verified algebra)
#pragma unroll
        for (int jt = 0; jt < 4; ++jt) {
            ushort4v u;
#pragma unroll
            for (int r = 0; r < 4; ++r) u[r] = f2bf(p[jt][r]);
            int frag = (w*2 + (jt >> 1))*64 + 16*(2*(jt & 1) + (g >> 1)) + m;
            *(ushort4v*)&PA[buf][frag*8 + 4*(g & 1)] = u;
        }

        __syncthreads();

        // ---- PV: O = alpha*O + P V (this wave: channels 64w..64w+63) ----
#pragma unroll
        for (int rt = 0; rt < 4; ++rt) {
            floatx4 a4 = *(const floatx4*)&AL[buf][16*rt + 4*g];
#pragma unroll
            for (int ct = 0; ct < 4; ++ct)
                accO[rt][ct] *= a4;
        }
#pragma unroll
        for (int ks = 0; ks < 2; ++ks) {
            bf16x8 pf[4];
#pragma unroll
            for (int rt = 0; rt < 4; ++rt)
                pf[rt] = *(const bf16x8*)&PA[buf][((rt*2 + ks)*64 + lane)*8];
#pragma unroll
            for (int ct = 0; ct < 4; ++ct)
#pragma unroll
                for (int rt = 0; rt < 4; ++rt)
                    accO[rt][ct] = __builtin_amdgcn_mfma_f32_16x16x32_bf16(
                                       pf[rt], vf[ks][ct], accO[rt][ct], 0, 0, 0);
        }
    }

    // ---- store unnormalized partial O (bf16) and per-query m,l ----
    const size_t tbase = ((size_t)(half*B_ + b)*64 + tile);
    unsigned short* Ob = Opart + tbase * (C_ * 64);
    float* ml = ML + tbase * 128;

    if (g == 0) {
        ml[16*w + m]      = mrow;
        ml[64 + 16*w + m] = lrow;
    }

#pragma unroll
    for (int rt = 0; rt < 4; ++rt)
#pragma unroll
        for (int ct = 0; ct < 4; ++ct) {
            int c = 64*w + 16*ct + m;
            ushort4v u4;
#pragma unroll
            for (int r = 0; r < 4; ++r) u4[r] = f2bf(accO[rt][ct][r]);
            *(ushort4v*)(Ob + (size_t)c*64 + 16*rt + 4*g) = u4;
        }
    (void)LL;
}

// ---------------------------------------------------------------------------
// Combine S split-K partials: w_s = e^{m_s-M}/L, L = sum_s e^{m_s-M} l_s;
// out = gamma * sum_s w_s O_s + x.
// ---------------------------------------------------------------------------
__global__ __launch_bounds__(256) void combine_kernel(
    const unsigned short* __restrict__ Opart, const float* __restrict__ ML,
    const float* __restrict__ x, const float* __restrict__ gamma,
    float* __restrict__ out, int S)
{
    __shared__ float sc[4][64];
    const int tile = blockIdx.x;
    const int b    = blockIdx.y;
    const int n0   = tile * 64;
    const int t    = threadIdx.x;

    if (t < 64) {
        float mv[4], lv[4];
        float M = -1e30f;
        for (int s = 0; s < S; ++s) {
            const float* ml = ML + ((size_t)(s*B_ + b)*64 + tile)*128;
            mv[s] = ml[t];
            lv[s] = ml[64 + t];
            M = fmaxf(M, mv[s]);
        }
        float L = 0.f;
        for (int s = 0; s < S; ++s) {
            float f = __expf(mv[s] - M);
            mv[s] = f;
            L += f * lv[s];
        }
        float gm = gamma[0];
        for (int s = 0; s < S; ++s) sc[s][t] = gm * mv[s] / L;
    }
    __syncthreads();

    const int nq = t & 15;
    const int c0 = t >> 4;
    const float* xb = x   + (size_t)b*C_*N_;
    float*       ob = out + (size_t)b*C_*N_;

    float sw[4][4];
    for (int s = 0; s < S; ++s)
#pragma unroll
        for (int k = 0; k < 4; ++k) sw[s][k] = sc[s][4*nq + k];

#pragma unroll 4
    for (int i = 0; i < 16; ++i) {
        int c = 16*i + c0;
        float4 x4 = *(const float4*)(xb + (size_t)c*N_ + n0 + 4*nq);
        float y0 = x4.x, y1 = x4.y, y2 = x4.z, y3 = x4.w;
        for (int s = 0; s < S; ++s) {
            const unsigned short* Os = Opart
                + ((size_t)(s*B_ + b)*64 + tile)*(C_*64);
            ushort4v a4 = *(const ushort4v*)(Os + (size_t)c*64 + 4*nq);
            y0 += sw[s][0]*bf2f(a4[0]);
            y1 += sw[s][1]*bf2f(a4[1]);
            y2 += sw[s][2]*bf2f(a4[2]);
            y3 += sw[s][3]*bf2f(a4[3]);
        }
        float4 y = {y0, y1, y2, y3};
        *(float4*)(ob + (size_t)c*N_ + n0 + 4*nq) = y;
    }
}

// ---------------------------------------------------------------------------
extern "C" void kernel_launch(void* const* d_in, const int* in_sizes, int n_in,
                              void* d_out, int out_size, void* d_ws, size_t ws_size,
                              hipStream_t stream) {
    const float* x     = (const float*)d_in[0];
    const float* Wq    = (const float*)d_in[1];
    const float* bq    = (const float*)d_in[2];
    const float* Wk    = (const float*)d_in[3];
    const float* bk    = (const float*)d_in[4];
    const float* Wv    = (const float*)d_in[5];
    const float* bv    = (const float*)d_in[6];
    const float* gamma = (const float*)d_in[7];
    float* out = (float*)d_out;

    unsigned short* Qg = (unsigned short*)d_ws;          // [B][N][64]   2 MB
    unsigned short* Kg = Qg + (size_t)B_*N_*D_;          // [B][N][64]   2 MB
    unsigned short* Vg = Kg + (size_t)B_*N_*D_;          // [B][C][N]    8 MB

    // split-K factor: 3 if workspace allows (exactly 3 blocks/CU), else 2
    const size_t base_b  = (size_t)12 * 1024 * 1024;
    const size_t per_s   = (size_t)2*B_*64*C_*64        // Opart bf16 (8 MB)
                         + (size_t)4*B_*64*128;         // ML fp32 (128 KB)
    int S = (ws_size >= base_b + 3*per_s) ? 3 : 2;

    unsigned short* Op = Vg + (size_t)B_*C_*N_;
    float*          ML = (float*)(Op + (size_t)S*B_*64*C_*64);

    proj_kernel<<<dim3(32, 3, 4), 256, 0, stream>>>(x, Wq, bq, Wk, bk, Wv, bv,
                                                    Qg, Kg, Vg);
    flash_kernel<<<dim3(64, S, 4), 256, 0, stream>>>(Qg, Kg, Vg, Op, ML);
    combine_kernel<<<dim3(64, 4), 256, 0, stream>>>(Op, ML, x, gamma, out, S);
}

// Round 5
// 235.560 us; speedup vs baseline: 1.4597x; 1.4597x over previous
//
#include <hip/hip_runtime.h>

#define B_ 4
#define C_ 256
#define N_ 4096
#define D_ 64

typedef __bf16 bf16x8 __attribute__((ext_vector_type(8)));
typedef float floatx4 __attribute__((ext_vector_type(4)));
typedef unsigned short ushort8v __attribute__((ext_vector_type(8)));
typedef unsigned short ushort4v __attribute__((ext_vector_type(4)));

static __device__ __forceinline__ unsigned short f2bf(float f) {
    unsigned int u = __builtin_bit_cast(unsigned int, f);
    u += 0x7fffu + ((u >> 16) & 1u);   // RNE
    return (unsigned short)(u >> 16);
}
static __device__ __forceinline__ float bf2f(unsigned short h) {
    unsigned int u = ((unsigned int)h) << 16;
    return __builtin_bit_cast(float, u);
}

// ---------------------------------------------------------------------------
// Convert kernel. z<4: x[b][c][n] fp32 -> xT[b][n][c] bf16 (LDS-tiled
// transpose, coalesced both sides). z==4: W{q,k,v} fp32 -> Wbf[384][256] bf16.
// ---------------------------------------------------------------------------
__global__ __launch_bounds__(256) void convert_kernel(
    const float* __restrict__ x,
    const float* __restrict__ Wq, const float* __restrict__ Wk,
    const float* __restrict__ Wv,
    unsigned short* __restrict__ xT, unsigned short* __restrict__ Wbf)
{
    if (blockIdx.z == 4) {
        int id = blockIdx.y * 64 + blockIdx.x;
        if (id >= 96) return;                       // 96*256*4 = 98304 = 384*256
        int e = (id * 256 + threadIdx.x) * 4;
        int f = e >> 8, c = e & 255;
        const float* src = (f < 64)  ? (Wq + (size_t)f * 256)
                         : (f < 128) ? (Wk + (size_t)(f - 64) * 256)
                                     : (Wv + (size_t)(f - 128) * 256);
        float4 v = *(const float4*)(src + c);
        ushort4v u;
        u[0] = f2bf(v.x); u[1] = f2bf(v.y); u[2] = f2bf(v.z); u[3] = f2bf(v.w);
        *(ushort4v*)(Wbf + e) = u;
        return;
    }

    __shared__ float Tt[64 * 68];
    const int n0 = blockIdx.x * 64;
    const int c0 = blockIdx.y * 64;
    const int b  = blockIdx.z;
    const int t  = threadIdx.x;

#pragma unroll
    for (int k = 0; k < 4; ++k) {
        int e   = t + 256 * k;
        int cc  = e >> 4;             // 0..63
        int nl4 = (e & 15) * 4;       // 0..60
        float4 v = *(const float4*)(x + ((size_t)b*C_ + c0 + cc)*N_ + n0 + nl4);
        Tt[(nl4+0)*68 + cc] = v.x;
        Tt[(nl4+1)*68 + cc] = v.y;
        Tt[(nl4+2)*68 + cc] = v.z;
        Tt[(nl4+3)*68 + cc] = v.w;
    }
    __syncthreads();
#pragma unroll
    for (int k = 0; k < 2; ++k) {
        int e  = t + 256 * k;
        int nl = e >> 3;              // 0..63
        int c8 = (e & 7) * 8;         // 0..56
        ushort8v u;
#pragma unroll
        for (int j = 0; j < 8; ++j) u[j] = f2bf(Tt[nl*68 + c8 + j]);
        *(ushort8v*)(xT + ((size_t)b*N_ + n0 + nl)*C_ + c0 + c8) = u;
    }
}

// ---------------------------------------------------------------------------
// MFMA projection: Y[f][n] = Wbf[f][c] * xT[n][c]^T + bias.
// f-tile 128 x n-tile 64 per block; wave w: f rows [f0+32w, +32).
// A-frags direct from Wbf rows, B-frags direct from xT rows (both 16B/lane).
// Epilogue bounces through LDS: f0==0 -> Q/K [n][64] (transposed read),
// f0>=128 -> V [c][n] (row read), all global stores coalesced 16B/lane.
// ---------------------------------------------------------------------------
__global__ __launch_bounds__(256, 3) void proj_kernel(
    const unsigned short* __restrict__ xT, const unsigned short* __restrict__ Wbf,
    const float* __restrict__ bq, const float* __restrict__ bk,
    const float* __restrict__ bv,
    unsigned short* __restrict__ Qg, unsigned short* __restrict__ Kg,
    unsigned short* __restrict__ Vg)
{
    __shared__ unsigned short Lt[128 * 72];   // pad 72 -> 16B-aligned rows

    const int n0 = blockIdx.x * 64;
    const int f0 = blockIdx.y * 128;
    const int b  = blockIdx.z;
    const int t  = threadIdx.x;
    const int w  = t >> 6;
    const int lane = t & 63;
    const int g  = lane >> 4;
    const int m  = lane & 15;

    // bias per (mt, r): f = f0 + 32w + 16mt + 4g + r
    float bias_[2][4];
#pragma unroll
    for (int mt = 0; mt < 2; ++mt)
#pragma unroll
        for (int r = 0; r < 4; ++r) {
            int fg = f0 + 32*w + 16*mt + 4*g + r;
            bias_[mt][r] = (fg < 64) ? bq[fg]
                         : (fg < 128) ? bk[fg - 64] : bv[fg - 128];
        }

    const unsigned short* Aw = Wbf + ((size_t)(f0 + 32*w + m))*C_ + 8*g;
    const unsigned short* Bx = xT + ((size_t)b*N_ + n0 + m)*C_ + 8*g;

    floatx4 acc[2][4];
#pragma unroll
    for (int mt = 0; mt < 2; ++mt)
#pragma unroll
        for (int nt = 0; nt < 4; ++nt) acc[mt][nt] = (floatx4){0.f,0.f,0.f,0.f};

    bf16x8 a_c[2], b_c[4];
#pragma unroll
    for (int mt = 0; mt < 2; ++mt) a_c[mt] = *(const bf16x8*)(Aw + mt*16*C_);
#pragma unroll
    for (int nt = 0; nt < 4; ++nt) b_c[nt] = *(const bf16x8*)(Bx + nt*16*C_);

    for (int ks = 0; ks < 8; ++ks) {
        bf16x8 a_n[2], b_n[4];
        int k1 = ((ks + 1) & 7) * 32;   // last prefetch wraps (unused)
#pragma unroll
        for (int mt = 0; mt < 2; ++mt)
            a_n[mt] = *(const bf16x8*)(Aw + mt*16*C_ + k1);
#pragma unroll
        for (int nt = 0; nt < 4; ++nt)
            b_n[nt] = *(const bf16x8*)(Bx + nt*16*C_ + k1);
#pragma unroll
        for (int mt = 0; mt < 2; ++mt)
#pragma unroll
            for (int nt = 0; nt < 4; ++nt)
                acc[mt][nt] = __builtin_amdgcn_mfma_f32_16x16x32_bf16(
                                  a_c[mt], b_c[nt], acc[mt][nt], 0, 0, 0);
#pragma unroll
        for (int mt = 0; mt < 2; ++mt) a_c[mt] = a_n[mt];
#pragma unroll
        for (int nt = 0; nt < 4; ++nt) b_c[nt] = b_n[nt];
    }

    // epilogue: bias + f2bf into LDS tile Lt[f_local][n_local]
#pragma unroll
    for (int mt = 0; mt < 2; ++mt)
#pragma unroll
        for (int nt = 0; nt < 4; ++nt)
#pragma unroll
            for (int r = 0; r < 4; ++r)
                Lt[(32*w + 16*mt + 4*g + r)*72 + 16*nt + m] =
                    f2bf(acc[mt][nt][r] + bias_[mt][r]);
    __syncthreads();

    if (f0 == 0) {
        // Q/K: [n][64] via transposed LDS read (same-dword lane pairs: free)
#pragma unroll
        for (int k = 0; k < 4; ++k) {
            int e   = t + 256 * k;
            int fq0 = (e >> 6) * 8;    // 0..120
            int nl  = e & 63;
            ushort8v u;
#pragma unroll
            for (int j = 0; j < 8; ++j) u[j] = Lt[(fq0 + j)*72 + nl];
            unsigned short* dst = (fq0 < 64)
                ? (Qg + ((size_t)b*N_ + n0 + nl)*D_ + fq0)
                : (Kg + ((size_t)b*N_ + n0 + nl)*D_ + (fq0 - 64));
            *(ushort8v*)dst = u;
        }
    } else {
        const int cb = f0 - 128;
#pragma unroll
        for (int k = 0; k < 4; ++k) {
            int e  = t + 256 * k;
            int fr = e >> 3;           // 0..127
            int n8 = (e & 7) * 8;      // 0..56
            ushort8v u = *(const ushort8v*)&Lt[fr*72 + n8];
            *(ushort8v*)(Vg + ((size_t)b*C_ + cb + fr)*N_ + n0 + n8) = u;
        }
    }
}

// ---------------------------------------------------------------------------
// MFMA flash attention, split-K 2 (R3 occupancy config + R4 cheap softmax).
// launch_bounds(256,2): 256-VGPR budget keeps all 16 V-frags + K-prefetch
// live across softmax (R4's (256,3) collapsed this -> 84 VGPR, +55% time).
// ---------------------------------------------------------------------------
__global__ __launch_bounds__(256, 2) void flash_kernel(
    const unsigned short* __restrict__ Qg, const unsigned short* __restrict__ Kg,
    const unsigned short* __restrict__ Vg,
    unsigned short* __restrict__ Opart, float* __restrict__ ML)
{
    __shared__ __align__(16) unsigned short PA[2][8 * 64 * 8];
    __shared__ float AL[2][64];

    const int tile = blockIdx.x;
    const int half = blockIdx.y;
    const int S    = gridDim.y;
    const int b    = blockIdx.z;
    const int n0   = tile * 64;
    const int t    = threadIdx.x;
    const int w    = t >> 6;
    const int lane = t & 63;
    const int g    = lane >> 4;
    const int m    = lane & 15;

    const unsigned short* Qb = Qg + ((size_t)b*N_ + n0)*D_;
    const unsigned short* Kb = Kg + (size_t)b*N_*D_;
    const unsigned short* Vb = Vg + (size_t)b*C_*N_;

    const int cstart = (64 * half) / S;
    const int cend   = (64 * (half + 1)) / S;

    bf16x8 qf[2];
#pragma unroll
    for (int ks = 0; ks < 2; ++ks)
        qf[ks] = *(const bf16x8*)(Qb + (size_t)(16*w + m)*D_ + 32*ks + 8*g);

    floatx4 accO[4][4];
#pragma unroll
    for (int rt = 0; rt < 4; ++rt)
#pragma unroll
        for (int ct = 0; ct < 4; ++ct)
            accO[rt][ct] = (floatx4){0.f, 0.f, 0.f, 0.f};

    float mrow = -1e30f, lrow = 0.f;

    bf16x8 kf[2][4];
#pragma unroll
    for (int ks = 0; ks < 2; ++ks)
#pragma unroll
        for (int jt = 0; jt < 4; ++jt)
            kf[ks][jt] = *(const bf16x8*)(Kb + (size_t)(cstart*64 + 16*jt + m)*D_
                                          + 32*ks + 8*g);

    for (int t64 = cstart; t64 < cend; ++t64) {
        const int j0  = t64 * 64;
        const int buf = (t64 - cstart) & 1;

        bf16x8 vf[2][4];
#pragma unroll
        for (int ks = 0; ks < 2; ++ks)
#pragma unroll
            for (int ct = 0; ct < 4; ++ct)
                vf[ks][ct] = *(const bf16x8*)(Vb + (size_t)(64*w + 16*ct + m)*N_
                                              + j0 + 32*ks + 8*g);

        // S^T = K*Q: col=lane&15=query, row=4g+r -> key 16jt+4g+r
        floatx4 accST[4];
#pragma unroll
        for (int jt = 0; jt < 4; ++jt) accST[jt] = (floatx4){0.f, 0.f, 0.f, 0.f};
#pragma unroll
        for (int ks = 0; ks < 2; ++ks)
#pragma unroll
            for (int jt = 0; jt < 4; ++jt)
                accST[jt] = __builtin_amdgcn_mfma_f32_16x16x32_bf16(
                                kf[ks][jt], qf[ks], accST[jt], 0, 0, 0);

        {
            int j1 = (j0 + 64) & (N_ - 1);
#pragma unroll
            for (int ks = 0; ks < 2; ++ks)
#pragma unroll
                for (int jt = 0; jt < 4; ++jt)
                    kf[ks][jt] = *(const bf16x8*)(Kb + (size_t)(j1 + 16*jt + m)*D_
                                                  + 32*ks + 8*g);
        }

        // online softmax: in-register over 16 keys/lane + 2 shfls
        float mx = -1e30f;
#pragma unroll
        for (int jt = 0; jt < 4; ++jt)
#pragma unroll
            for (int r = 0; r < 4; ++r) mx = fmaxf(mx, accST[jt][r]);
        mx = fmaxf(mx, __shfl_xor(mx, 16));
        mx = fmaxf(mx, __shfl_xor(mx, 32));
        float mnew  = fmaxf(mrow, mx);
        float alpha = __expf(mrow - mnew);
        mrow = mnew;
        float p[4][4];
        float rs = 0.f;
#pragma unroll
        for (int jt = 0; jt < 4; ++jt)
#pragma unroll
            for (int r = 0; r < 4; ++r) {
                float e = __expf(accST[jt][r] - mnew);
                p[jt][r] = e;
                rs += e;
            }
        rs += __shfl_xor(rs, 16);
        rs += __shfl_xor(rs, 32);
        lrow = lrow * alpha + rs;

        if (g == 0) AL[buf][16*w + m] = alpha;

        // P -> LDS, direct b64 stores into A-frag layout
#pragma unroll
        for (int jt = 0; jt < 4; ++jt) {
            ushort4v u;
#pragma unroll
            for (int r = 0; r < 4; ++r) u[r] = f2bf(p[jt][r]);
            int frag = (w*2 + (jt >> 1))*64 + 16*(2*(jt & 1) + (g >> 1)) + m;
            *(ushort4v*)&PA[buf][frag*8 + 4*(g & 1)] = u;
        }

        __syncthreads();

        // PV: O = alpha*O + P V (this wave: channels 64w..64w+63)
#pragma unroll
        for (int rt = 0; rt < 4; ++rt) {
            floatx4 a4 = *(const floatx4*)&AL[buf][16*rt + 4*g];
#pragma unroll
            for (int ct = 0; ct < 4; ++ct)
                accO[rt][ct] *= a4;
        }
#pragma unroll
        for (int ks = 0; ks < 2; ++ks) {
            bf16x8 pf[4];
#pragma unroll
            for (int rt = 0; rt < 4; ++rt)
                pf[rt] = *(const bf16x8*)&PA[buf][((rt*2 + ks)*64 + lane)*8];
#pragma unroll
            for (int ct = 0; ct < 4; ++ct)
#pragma unroll
                for (int rt = 0; rt < 4; ++rt)
                    accO[rt][ct] = __builtin_amdgcn_mfma_f32_16x16x32_bf16(
                                       pf[rt], vf[ks][ct], accO[rt][ct], 0, 0, 0);
        }
    }

    // store unnormalized partial O (bf16) and per-query m,l
    const size_t tbase = ((size_t)(half*B_ + b)*64 + tile);
    unsigned short* Ob = Opart + tbase * (C_ * 64);
    float* ml = ML + tbase * 128;

    if (g == 0) {
        ml[16*w + m]      = mrow;
        ml[64 + 16*w + m] = lrow;
    }

#pragma unroll
    for (int rt = 0; rt < 4; ++rt)
#pragma unroll
        for (int ct = 0; ct < 4; ++ct) {
            int c = 64*w + 16*ct + m;
            ushort4v u4;
#pragma unroll
            for (int r = 0; r < 4; ++r) u4[r] = f2bf(accO[rt][ct][r]);
            *(ushort4v*)(Ob + (size_t)c*64 + 16*rt + 4*g) = u4;
        }
}

// ---------------------------------------------------------------------------
// Combine S split-K partials: w_s = e^{m_s-M}/L, L = sum_s e^{m_s-M} l_s;
// out = gamma * sum_s w_s O_s + x.
// ---------------------------------------------------------------------------
__global__ __launch_bounds__(256) void combine_kernel(
    const unsigned short* __restrict__ Opart, const float* __restrict__ ML,
    const float* __restrict__ x, const float* __restrict__ gamma,
    float* __restrict__ out, int S)
{
    __shared__ float sc[4][64];
    const int tile = blockIdx.x;
    const int b    = blockIdx.y;
    const int n0   = tile * 64;
    const int t    = threadIdx.x;

    if (t < 64) {
        float mv[4], lv[4];
        float M = -1e30f;
        for (int s = 0; s < S; ++s) {
            const float* ml = ML + ((size_t)(s*B_ + b)*64 + tile)*128;
            mv[s] = ml[t];
            lv[s] = ml[64 + t];
            M = fmaxf(M, mv[s]);
        }
        float L = 0.f;
        for (int s = 0; s < S; ++s) {
            float f = __expf(mv[s] - M);
            mv[s] = f;
            L += f * lv[s];
        }
        float gm = gamma[0];
        for (int s = 0; s < S; ++s) sc[s][t] = gm * mv[s] / L;
    }
    __syncthreads();

    const int nq = t & 15;
    const int c0 = t >> 4;
    const float* xb = x   + (size_t)b*C_*N_;
    float*       ob = out + (size_t)b*C_*N_;

    float sw[4][4];
    for (int s = 0; s < S; ++s)
#pragma unroll
        for (int k = 0; k < 4; ++k) sw[s][k] = sc[s][4*nq + k];

#pragma unroll 4
    for (int i = 0; i < 16; ++i) {
        int c = 16*i + c0;
        float4 x4 = *(const float4*)(xb + (size_t)c*N_ + n0 + 4*nq);
        float y0 = x4.x, y1 = x4.y, y2 = x4.z, y3 = x4.w;
        for (int s = 0; s < S; ++s) {
            const unsigned short* Os = Opart
                + ((size_t)(s*B_ + b)*64 + tile)*(C_*64);
            ushort4v a4 = *(const ushort4v*)(Os + (size_t)c*64 + 4*nq);
            y0 += sw[s][0]*bf2f(a4[0]);
            y1 += sw[s][1]*bf2f(a4[1]);
            y2 += sw[s][2]*bf2f(a4[2]);
            y3 += sw[s][3]*bf2f(a4[3]);
        }
        float4 y = {y0, y1, y2, y3};
        *(float4*)(ob + (size_t)c*N_ + n0 + 4*nq) = y;
    }
}

// ---------------------------------------------------------------------------
extern "C" void kernel_launch(void* const* d_in, const int* in_sizes, int n_in,
                              void* d_out, int out_size, void* d_ws, size_t ws_size,
                              hipStream_t stream) {
    const float* x     = (const float*)d_in[0];
    const float* Wq    = (const float*)d_in[1];
    const float* bq    = (const float*)d_in[2];
    const float* Wk    = (const float*)d_in[3];
    const float* bk    = (const float*)d_in[4];
    const float* Wv    = (const float*)d_in[5];
    const float* bv    = (const float*)d_in[6];
    const float* gamma = (const float*)d_in[7];
    float* out = (float*)d_out;

    // ws layout (29.9 MB total; Op aliases xT — proj reads xT before flash
    // writes Op, stream-ordered):
    unsigned short* Qg = (unsigned short*)d_ws;            // 2 MiB
    unsigned short* Kg = Qg + (size_t)B_*N_*D_;            // 2 MiB
    unsigned short* Vg = Kg + (size_t)B_*N_*D_;            // 8 MiB
    unsigned short* xT = Vg + (size_t)B_*C_*N_;            // 8 MiB (@12.58M)
    unsigned short* Op = xT;                               // 16 MiB (aliases xT)
    float* ML = (float*)(Op + (size_t)2*B_*64*C_*64);      // 256 KiB (@29.36M)
    unsigned short* Wbf = (unsigned short*)(ML + (size_t)2*B_*64*128); // 192 KiB

    convert_kernel<<<dim3(64, 4, 5), 256, 0, stream>>>(x, Wq, Wk, Wv, xT, Wbf);
    proj_kernel<<<dim3(64, 3, 4), 256, 0, stream>>>(xT, Wbf, bq, bk, bv,
                                                    Qg, Kg, Vg);
    flash_kernel<<<dim3(64, 2, 4), 256, 0, stream>>>(Qg, Kg, Vg, Op, ML);
    combine_kernel<<<dim3(64, 4), 256, 0, stream>>>(Op, ML, x, gamma, out, 2);
}